// Round 7
// baseline (433.659 us; speedup 1.0000x reference)
//
#include <hip/hip_runtime.h>

typedef __attribute__((ext_vector_type(8))) short bf16x8;
typedef __attribute__((ext_vector_type(4))) float f32x4;
typedef unsigned short ushort_t;

// ---------------------------------------------------------------------------
// fp32 -> bf16 RNE helpers
// ---------------------------------------------------------------------------
__device__ inline unsigned f2bf_rnd(float f) {
    unsigned u = __float_as_uint(f);
    return u + 0x7FFFu + ((u >> 16) & 1u);   // high 16 bits = RNE bf16
}

__device__ inline void split8(f32x4 a, f32x4 b, bf16x8& hv, bf16x8& lv) {
    float f[8] = {a.x, a.y, a.z, a.w, b.x, b.y, b.z, b.w};
    unsigned r[8], l[8];
#pragma unroll
    for (int j = 0; j < 8; ++j) r[j] = f2bf_rnd(f[j]);
#pragma unroll
    for (int j = 0; j < 8; ++j) {
        float hf = __uint_as_float(r[j] & 0xFFFF0000u);
        l[j] = f2bf_rnd(f[j] - hf);
    }
    union { unsigned u[4]; bf16x8 v; } H, L;
#pragma unroll
    for (int p = 0; p < 4; ++p) {
        H.u[p] = __builtin_amdgcn_perm(r[2 * p + 1], r[2 * p], 0x07060302u);
        L.u[p] = __builtin_amdgcn_perm(l[2 * p + 1], l[2 * p], 0x07060302u);
    }
    hv = H.v; lv = L.v;
}

// ---------------------------------------------------------------------------
// Kernel 1: pack W_in [64][1024] fp32 -> Wp bf16 hi/lo in MFMA-fragment layout
// Wp ushort idx = ch*4096 + hl*2048 + kg*512 + n*8 + j ; k = ch*32 + kg*8 + j
// ---------------------------------------------------------------------------
__global__ void pack_w_kernel(const float* __restrict__ Win, ushort_t* __restrict__ Wp) {
    int idx = blockIdx.x * 256 + threadIdx.x;   // 0..65535
    int j  = idx & 7;
    int n  = (idx >> 3) & 63;
    int kg = (idx >> 9) & 3;
    int ch = idx >> 11;                          // 0..31
    int k  = ch * 32 + kg * 8 + j;
    float v = Win[n * 1024 + k];
    unsigned hb = f2bf_rnd(v) >> 16;
    float hf = __uint_as_float(hb << 16);
    unsigned lb = f2bf_rnd(v - hf) >> 16;
    Wp[ch * 4096 + 0    + kg * 512 + n * 8 + j] = (ushort_t)hb;
    Wp[ch * 4096 + 2048 + kg * 512 + n * 8 + j] = (ushort_t)lb;
}

// ---------------------------------------------------------------------------
// Kernel 2: ext = x @ W_in^T + b_in  via bf16 MFMA, 3-term hi/lo split.
// M=131072, N=64, K=1024.  BM=32, BK=256 floats (1KB/row/tile), 4 K-tiles.
// 256 threads = 4 waves; wave w owns output cols nq=w (16 of 64); each wave
// computes both m-quads (rows 0..31) over full K.
//   - A global loads: each wave-instruction reads ONE FULL 1KB row segment
//     (64 lanes x 16B contiguous) -> DRAM/channel-friendly streaming.
//   - Per-block K-phase desync (kt order rotated by blockIdx&3) despreads
//     the chip-wide column hotspot across HBM channels.
//   - Plain cached loads (no nontemporal): L2 smooths re-requests.
//   - A tile in LDS, row stride 260 floats (pad 4) -> 2-way banks (free).
//   - B fragments direct from L2-resident Wp (256 KB), no staging.
// ---------------------------------------------------------------------------
__global__ __launch_bounds__(256, 4) void gemm_ext_kernel(const float* __restrict__ x,
                                                          const ushort_t* __restrict__ Wp,
                                                          const float* __restrict__ bin,
                                                          float* __restrict__ ext) {
    __shared__ __align__(16) float Asm[32 * 260];   // 33.3 KB

    const int tid  = threadIdx.x;        // 0..255
    const int lane = tid & 63;
    const int nq   = tid >> 6;           // wave id = output col quad
    const int l15  = lane & 15;
    const int lg   = lane >> 4;          // k-group 0..3
    const int phase = blockIdx.x & 3;

    const long rowbase = (long)blockIdx.x * 32;

    // A-load coords: instr i covers rows 4i..4i+3; this thread's row/offset
    const int arow = (tid >> 6);         // + 4*i
    const int aoff = (lane & 63) * 4;    // float offset within 1KB row segment

    f32x4 acc[2];
    acc[0] = (f32x4){0.f, 0.f, 0.f, 0.f};
    acc[1] = (f32x4){0.f, 0.f, 0.f, 0.f};

    f32x4 Areg[8];

    // prologue: load tile kto=0 (kt = phase)
    {
        const float* xb = x + rowbase * 1024 + (long)phase * 256 + aoff;
#pragma unroll
        for (int i = 0; i < 8; ++i)
            Areg[i] = *(const f32x4*)(xb + (long)(4 * i + arow) * 1024);
    }

    const ushort_t* bb = Wp + lg * 512 + (nq * 16 + l15) * 8;

#pragma unroll 1
    for (int kto = 0; kto < 4; ++kto) {
        const int kt = (kto + phase) & 3;
        __syncthreads();   // previous tile's LDS reads done
        // commit staged tile (waits on global loads)
#pragma unroll
        for (int i = 0; i < 8; ++i)
            *(f32x4*)(Asm + (4 * i + arow) * 260 + aoff) = Areg[i];
        __syncthreads();   // tile visible

        // prefetch next tile (covered by this tile's compute phase)
        if (kto < 3) {
            const int ktn = (kto + 1 + phase) & 3;
            const float* xb = x + rowbase * 1024 + (long)ktn * 256 + aoff;
#pragma unroll
            for (int i = 0; i < 8; ++i)
                Areg[i] = *(const f32x4*)(xb + (long)(4 * i + arow) * 1024);
        }

        // compute: 8 k-chunks of 32
#pragma unroll 2
        for (int c = 0; c < 8; ++c) {
            const int ch = kt * 8 + c;
            const ushort_t* bp = bb + ch * 4096;
            bf16x8 bh = *(const bf16x8*)(bp);
            bf16x8 bl = *(const bf16x8*)(bp + 2048);
#pragma unroll
            for (int mq = 0; mq < 2; ++mq) {
                const float* ap = Asm + (mq * 16 + l15) * 260 + c * 32 + lg * 8;
                f32x4 a0 = *(const f32x4*)ap;
                f32x4 a1 = *(const f32x4*)(ap + 4);
                bf16x8 Ahi, Alo;
                split8(a0, a1, Ahi, Alo);
                acc[mq] = __builtin_amdgcn_mfma_f32_16x16x32_bf16(Ahi, bh, acc[mq], 0, 0, 0);
                acc[mq] = __builtin_amdgcn_mfma_f32_16x16x32_bf16(Ahi, bl, acc[mq], 0, 0, 0);
                acc[mq] = __builtin_amdgcn_mfma_f32_16x16x32_bf16(Alo, bh, acc[mq], 0, 0, 0);
            }
        }
    }

    // epilogue: add bias, store.  C/D map: col = lane&15, row = (lane>>4)*4 + r
    const float bias = bin[nq * 16 + l15];
#pragma unroll
    for (int mq = 0; mq < 2; ++mq) {
        long r0 = rowbase + mq * 16 + lg * 4;
#pragma unroll
        for (int r = 0; r < 4; ++r) {
            ext[(r0 + r) * 64 + nq * 16 + l15] = acc[mq][r] + bias;
        }
    }
}

// ---------------------------------------------------------------------------
// Kernel 3: recurrent scan.  One block (1 wave, 64 threads) per batch element.
// (byte-identical to R4/R5/R6 for attribution)
// ---------------------------------------------------------------------------
__global__ __launch_bounds__(64) void scan_kernel(const float* __restrict__ ext,
                                                  const float* __restrict__ Wrec,
                                                  const float* __restrict__ brec,
                                                  float* __restrict__ states) {
    const int b = blockIdx.x;
    const int h = threadIdx.x;   // 0..63

    float w[64];
#pragma unroll
    for (int i = 0; i < 16; ++i)
        *(float4*)&w[i * 4] = *(const float4*)&Wrec[h * 64 + i * 4];
    const float bias = brec[h];

    __shared__ float in_lds[2][64];

    const float* ep = ext + (size_t)b * 512 * 64 + h;
    float* sp = states + (size_t)b * 512 * 64 + h;

    float s = 0.f;
    float e0 = ep[0];
    float e1 = ep[64];

    for (int t = 0; t < 512; ++t) {
        float in = s + e0;
        in_lds[t & 1][h] = in;
        e0 = e1;
        if (t + 2 < 512) e1 = ep[(size_t)(t + 2) * 64];
        // single-wave block: writes visible after lgkmcnt(0); no barrier, no vmcnt drain
        asm volatile("s_waitcnt lgkmcnt(0)" ::: "memory");

        float a0 = bias, a1 = 0.f, a2 = 0.f, a3 = 0.f;
#pragma unroll
        for (int i = 0; i < 16; ++i) {
            float4 v = *(const float4*)&in_lds[t & 1][i * 4];
            a0 += v.x * w[i * 4 + 0];
            a1 += v.y * w[i * 4 + 1];
            a2 += v.z * w[i * 4 + 2];
            a3 += v.w * w[i * 4 + 3];
        }
        s = fmaxf((a0 + a1) + (a2 + a3), 0.f);
        sp[(size_t)t * 64] = s;
    }
}

// ---------------------------------------------------------------------------
// Kernel 4: output head.  out = relu(states @ W_o1^T + b_o1) @ W_o2^T + b_o2
// (byte-identical to R4/R5/R6)
// ---------------------------------------------------------------------------
__global__ __launch_bounds__(256) void head_kernel(const float* __restrict__ states,
                                                   const float* __restrict__ Wo1,
                                                   const float* __restrict__ bo1,
                                                   const float* __restrict__ Wo2,
                                                   const float* __restrict__ bo2,
                                                   float* __restrict__ out) {
    __shared__ float W1t[64][32];   // W1t[k][j] = Wo1[j][k]
    __shared__ float w2s[64];
    __shared__ float b1s[32];
    __shared__ float b2s[2];

    const int tid = threadIdx.x;
    for (int idx = tid; idx < 2048; idx += 256) {
        int j = idx >> 6, k = idx & 63;
        W1t[k][j] = Wo1[idx];
    }
    if (tid < 64) w2s[tid] = Wo2[tid];
    if (tid < 32) b1s[tid] = bo1[tid];
    if (tid < 2)  b2s[tid] = bo2[tid];
    __syncthreads();

    const size_t row = (size_t)blockIdx.x * 256 + tid;  // 0..131071
    const float* srow = states + row * 64;

    float st[64];
#pragma unroll
    for (int i = 0; i < 16; ++i)
        *(float4*)&st[i * 4] = *(const float4*)&srow[i * 4];

    float4 hacc[8];
#pragma unroll
    for (int j4 = 0; j4 < 8; ++j4) hacc[j4] = (float4){0.f, 0.f, 0.f, 0.f};

#pragma unroll
    for (int k = 0; k < 64; ++k) {
        float sk = st[k];
#pragma unroll
        for (int j4 = 0; j4 < 8; ++j4) {
            float4 wv = *(const float4*)&W1t[k][j4 * 4];
            hacc[j4].x += sk * wv.x;
            hacc[j4].y += sk * wv.y;
            hacc[j4].z += sk * wv.z;
            hacc[j4].w += sk * wv.w;
        }
    }

    float o0 = b2s[0], o1 = b2s[1];
#pragma unroll
    for (int j4 = 0; j4 < 8; ++j4) {
        float4 bv = *(const float4*)&b1s[j4 * 4];
        float hj[4] = {fmaxf(hacc[j4].x + bv.x, 0.f), fmaxf(hacc[j4].y + bv.y, 0.f),
                       fmaxf(hacc[j4].z + bv.z, 0.f), fmaxf(hacc[j4].w + bv.w, 0.f)};
#pragma unroll
        for (int r = 0; r < 4; ++r) {
            int j = j4 * 4 + r;
            o0 += hj[r] * w2s[j];
            o1 += hj[r] * w2s[32 + j];
        }
    }
    float2 ov = {o0, o1};
    *(float2*)&out[row * 2] = ov;
}

// ---------------------------------------------------------------------------
extern "C" void kernel_launch(void* const* d_in, const int* in_sizes, int n_in,
                              void* d_out, int out_size, void* d_ws, size_t ws_size,
                              hipStream_t stream) {
    (void)in_sizes; (void)n_in; (void)out_size; (void)ws_size;

    const float* x     = (const float*)d_in[0];
    const float* W_in  = (const float*)d_in[1];
    const float* b_in  = (const float*)d_in[2];
    const float* W_rec = (const float*)d_in[3];
    const float* b_rec = (const float*)d_in[4];
    const float* W_o1  = (const float*)d_in[5];
    const float* b_o1  = (const float*)d_in[6];
    const float* W_o2  = (const float*)d_in[7];
    const float* b_o2  = (const float*)d_in[8];
    float* out = (float*)d_out;

    char* ws = (char*)d_ws;
    ushort_t* Wp   = (ushort_t*)ws;                                  // 256 KB
    float* ext     = (float*)(ws + (1u << 20));                      // 32 MB
    float* states  = (float*)(ws + (1u << 20) + (32u << 20));        // 32 MB

    pack_w_kernel<<<256, 256, 0, stream>>>(W_in, Wp);
    gemm_ext_kernel<<<4096, 256, 0, stream>>>(x, Wp, b_in, ext);
    scan_kernel<<<256, 64, 0, stream>>>(ext, W_rec, b_rec, states);
    head_kernel<<<512, 256, 0, stream>>>(states, W_o1, b_o1, W_o2, b_o2, out);
}